// Round 19
// baseline (558.351 us; speedup 1.0000x reference)
//
#include <hip/hip_runtime.h>
#include <cfloat>

#define BB 64
#define NPERB 2048
#define KNN 16
#define NTOT (BB*NPERB)
#define NCAND 24

typedef __bf16 bf16x8 __attribute__((ext_vector_type(8)));
typedef float  f32x4  __attribute__((ext_vector_type(4)));

__device__ __forceinline__ unsigned int med3u(unsigned int a, unsigned int b, unsigned int c) {
    unsigned int d;
    asm("v_med3_u32 %0, %1, %2, %3" : "=v"(d) : "v"(a), "v"(b), "v"(c));
    return d;
}

__device__ __forceinline__ unsigned short bf16rn(float f) {
    unsigned int u = __float_as_uint(f);
    u += 0x7fffu + ((u >> 16) & 1u);
    return (unsigned short)(u >> 16);
}
__device__ __forceinline__ unsigned int pk2(float a, float b) {
    return ((unsigned int)bf16rn(b) << 16) | (unsigned int)bf16rn(a);
}

// Kernel 1: R12-measured version (part of the 531us best). W staged in LDS
// [o][f], wave-uniform b128 broadcasts. (R13 lesson: weights-in-VGPR kills
// occupancy; R7/R8 lesson: per-(o,f) global w loads thrash L1.)
__global__ __launch_bounds__(256) void k_transform(const float4* __restrict__ x4,
    const float* __restrict__ w, const float* __restrict__ bias,
    float* __restrict__ Aout, float* __restrict__ Bvv, float* __restrict__ sqnp,
    uint4* __restrict__ xbu4)
{
    __shared__ __align__(16) float wm[64*64];    // (w1-w2)[o][f]
    __shared__ __align__(16) float w2m[64*64];   // w2[o][f]
    const int t = threadIdx.x;
    const int r = blockIdx.x * 256 + t;

#pragma unroll
    for (int i = 0; i < 16; ++i) {
        int e = t + i*256;
        int o = e >> 6, f = e & 63;
        float w1 = w[o*128 + f];
        float w2 = w[o*128 + 64 + f];
        wm[e]  = w1 - w2;
        w2m[e] = w2;
    }

    float xr[64];
#pragma unroll
    for (int j = 0; j < 16; ++j) {
        float4 v = x4[(size_t)r * 16 + j];
        xr[4*j+0] = v.x; xr[4*j+1] = v.y; xr[4*j+2] = v.z; xr[4*j+3] = v.w;
    }

    // numpy pairwise-order sum of squares (unchanged op tree)
    {
        float rr[8];
#pragma unroll
        for (int j = 0; j < 8; ++j) rr[j] = __fmul_rn(xr[j], xr[j]);
#pragma unroll
        for (int i = 1; i < 8; ++i)
#pragma unroll
            for (int j = 0; j < 8; ++j)
                rr[j] = __fadd_rn(rr[j], __fmul_rn(xr[8*i + j], xr[8*i + j]));
        float t01 = __fadd_rn(rr[0], rr[1]);
        float t23 = __fadd_rn(rr[2], rr[3]);
        float t45 = __fadd_rn(rr[4], rr[5]);
        float t67 = __fadd_rn(rr[6], rr[7]);
        sqnp[r] = __fadd_rn(__fadd_rn(t01, t23), __fadd_rn(t45, t67));
    }

    // bf16 copy (identical bytes)
#pragma unroll
    for (int i = 0; i < 8; ++i) {
        uint4 u;
        u.x = pk2(xr[8*i+0], xr[8*i+1]);
        u.y = pk2(xr[8*i+2], xr[8*i+3]);
        u.z = pk2(xr[8*i+4], xr[8*i+5]);
        u.w = pk2(xr[8*i+6], xr[8*i+7]);
        xbu4[(size_t)r * 8 + i] = u;
    }

    __syncthreads();   // weights staged

    for (int o = 0; o < 64; o += 4) {
        float a4[4], b4[4];
#pragma unroll
        for (int oo = 0; oo < 4; ++oo) {
            const float* wmr  = &wm [(o + oo)*64];
            const float* w2mr = &w2m[(o + oo)*64];
            float a1 = 0.f, a2 = 0.f;
#pragma unroll
            for (int fi = 0; fi < 16; ++fi) {
                f32x4 wa = *(const f32x4*)&wmr [fi*4];
                f32x4 wb = *(const f32x4*)&w2mr[fi*4];
#pragma unroll
                for (int k = 0; k < 4; ++k) {
                    float xv = xr[fi*4 + k];
                    a1 = __builtin_fmaf(xv, wa[k], a1);
                    a2 = __builtin_fmaf(xv, wb[k], a2);
                }
            }
            a4[oo] = __fadd_rn(a1, bias[o + oo]);
            b4[oo] = a2;
        }
        *(float4*)&Aout[(size_t)r * 64 + o] = make_float4(a4[0], a4[1], a4[2], a4[3]);
        *(float4*)&Bvv [(size_t)r * 64 + o] = make_float4(b4[0], b4[1], b4[2], b4[3]);
    }
}

// Kernel 2 (R19 edit): global_load_lds staging. R15/R18 showed the spills
// (WRITE 79.9MB) persist at 48 VGPR regardless of prefetch-reg count; the fix
// is removing staging registers ENTIRELY. New tile layout: linear 128B rows
// (no pad) with XOR-16B-slot swizzle, rule #21 compliant:
//   LDS(row, c16) = global(row, c16 ^ (row&7))
//   write: linear dest (gll base+lane*16), source col16 = (l&7)^((l>>3)&7)
//   read : bcur[pt*64 + ((q ^ (pt&7))*8)]  for q = qd (a0) / qd+4 (a1)
// Read start-bank = (q^(ln&7))*4 -> 8 lanes per 4-bank group, SAME minimal
// serialization as the old 72-stride layout -> no read-bank regression.
// Flight: tile ct+1 issued at top of iter ct, drained at iter-ct-end barrier
// (~full compute). LDS 28160 -> 26112 (6 blocks/CU ceiling).
// Tripwire: WRITE_SIZE must drop 79.9 -> ~24.6MB (spills gone).
__global__ __launch_bounds__(256, 5) void k_topk(const float4* __restrict__ x4,
    const uint4* __restrict__ xb, const float* __restrict__ sq, int* __restrict__ nbr)
{
    // phase1: bsh0 0..8192 | bsh1 8192..16384 | rsh 16384..25600 | sqc 25600..26112
    // phase2: cand 0..17408 | cand24 17408..20480
    __shared__ __align__(16) char smem[26112];
    unsigned short* bsh0 = (unsigned short*)smem;
    unsigned short* bsh1 = (unsigned short*)(smem + 8192);
    unsigned short* rsh  = (unsigned short*)(smem + 16384);
    float* sqc           = (float*)(smem + 25600);     // [2][64]
    unsigned int* cand   = (unsigned int*)smem;        // 64 rows x 68
    unsigned short* cand24 = (unsigned short*)(smem + 17408);

    int t = threadIdx.x;
    int lane = t & 63;
    int w = t >> 6;
    int ln = lane & 15, qd = lane >> 4;
    int batch = blockIdx.x >> 5;
    int strip = blockIdx.x & 31;
    int rbase = batch * NPERB;
    int r0g = rbase + strip * 64;

    unsigned int ks[16];
#pragma unroll
    for (int j = 0; j < 16; ++j) ks[j] = 0xFFFFFFFFu;

    // --- gll staging: zero prefetch registers ---
    const int rowl = lane >> 3;                       // 0..7 within segment
    const int c16s = (lane & 7) ^ (rowl & 7);         // inverse-swizzled source col16
    auto issue_tile = [&](int ct_, int buf_) {
        char* base = smem + buf_*8192;
#pragma unroll
        for (int i = 0; i < 2; ++i) {
            int seg = w*2 + i;                        // 0..7
            int row = seg*8 + rowl;                   // tile row 0..63
            const uint4* src = xb + ((size_t)rbase + ct_*64 + row)*8 + c16s;
            __builtin_amdgcn_global_load_lds(
                (const __attribute__((address_space(1))) void*)src,
                (__attribute__((address_space(3))) void*)(base + seg*1024), 16, 0, 0);
        }
        if (w == 0) {                                 // wave-uniform guard
            const float* ssrc = sq + rbase + ct_*64 + lane;
            __builtin_amdgcn_global_load_lds(
                (const __attribute__((address_space(1))) void*)ssrc,
                (__attribute__((address_space(3))) void*)(sqc + buf_*64), 4, 0, 0);
        }
    };

    // --- prologue: rsh (72-stride, reg path, once) + tile0 via gll ---
    {
        const uint4* src = xb + (size_t)r0g * 8;
#pragma unroll
        for (int i = 0; i < 2; ++i) {
            int l = t + i*256;
            uint4 v = src[l];
            *(uint4*)&rsh[(l >> 3)*72 + (l & 7)*8] = v;
        }
    }
    issue_tile(0, 0);
    __syncthreads();                        // drains rsh ds_writes + tile0 gll
    bf16x8 rf0 = *(const bf16x8*)&rsh[(w*16 + ln)*72 + qd*8];
    bf16x8 rf1 = *(const bf16x8*)&rsh[(w*16 + ln)*72 + 32 + qd*8];
    float sqr16 = sq[r0g + w*16 + ln] + 16.f;

    // --- main loop: invariant at top: buf[ct&1] = tile ct (drained) ---
    for (int ct = 0; ct < 32; ++ct) {
        if (ct < 31) issue_tile(ct + 1, (ct + 1) & 1);  // flies across compute
        const unsigned short* bcur = (ct & 1) ? bsh1 : bsh0;
        const float* sqcur = sqc + (ct & 1)*64;
#pragma unroll
        for (int ct2 = 0; ct2 < 4; ++ct2) {
            int pt = ct2*16 + ln;
            int sw = pt & 7;
            bf16x8 a0 = *(const bf16x8*)&bcur[pt*64 + ((qd       ^ sw) * 8)];
            bf16x8 a1 = *(const bf16x8*)&bcur[pt*64 + (((qd + 4) ^ sw) * 8)];
            f32x4 acc = {0.f, 0.f, 0.f, 0.f};
            acc = __builtin_amdgcn_mfma_f32_16x16x32_bf16(a0, rf0, acc, 0, 0, 0);
            acc = __builtin_amdgcn_mfma_f32_16x16x32_bf16(a1, rf1, acc, 0, 0, 0);
            f32x4 sc4 = *(const f32x4*)&sqcur[ct2*16 + qd*4];
            int idxb = ct*64 + ct2*16 + qd*4;
#pragma unroll
            for (int j = 0; j < 4; ++j) {
                float s = fmaf(-2.f, acc[j], sc4[j] + sqr16);   // > 0 always
                unsigned int u = (__float_as_uint(s) & 0xFFFFF800u) | (unsigned int)(idxb + j);
#pragma unroll
                for (int jj = 15; jj >= 1; --jj) ks[jj] = med3u(u, ks[jj-1], ks[jj]);
                ks[0] = min(ks[0], u);
            }
        }
        __syncthreads();                    // drains next tile's gll + lgkm
    }

    // dump per-lane keys
    {
        int r = w*16 + ln;
#pragma unroll
        for (int j = 0; j < 16; ++j) cand[r*68 + qd*16 + j] = ks[j];
    }
    __syncthreads();

    // merge to bf16-top-24 per row
    if (t < 64) {
        unsigned int m24[NCAND];
#pragma unroll
        for (int j = 0; j < NCAND; ++j) m24[j] = 0xFFFFFFFFu;
        for (int i = 0; i < 64; ++i) {
            unsigned int u = cand[t*68 + i];
#pragma unroll
            for (int jj = NCAND-1; jj >= 1; --jj) m24[jj] = med3u(u, m24[jj-1], m24[jj]);
            m24[0] = min(m24[0], u);
        }
#pragma unroll
        for (int j = 0; j < NCAND; ++j) cand24[t*NCAND + j] = (unsigned short)(m24[j] & 0x7FFu);
    }
    __syncthreads();

    // np-exact rescore (R6-verified chain): 4 groups x 6 candidates per row
    {
        int r = t & 63, grp = t >> 6;
        float sqr = sq[r0g + r];
        float4 xrA[8];
#pragma unroll
        for (int i = 0; i < 8; ++i) xrA[i] = x4[(size_t)(r0g + r)*16 + i];
        float* kdf = (float*)cand;
#pragma unroll
        for (int m6 = 0; m6 < 6; ++m6) {
            int m = grp*6 + m6;
            int c = (int)cand24[r*NCAND + m];
            const float4* xb4 = &x4[(size_t)(rbase + c)*16];
            float dot = 0.f;
#pragma unroll
            for (int i = 0; i < 8; ++i) {
                float4 a = xrA[i]; float4 b = xb4[i];
                dot = fmaf(a.x, b.x, dot); dot = fmaf(a.y, b.y, dot);
                dot = fmaf(a.z, b.z, dot); dot = fmaf(a.w, b.w, dot);
            }
#pragma unroll
            for (int i = 8; i < 16; ++i) {
                float4 a = x4[(size_t)(r0g + r)*16 + i]; float4 b = xb4[i];
                dot = fmaf(a.x, b.x, dot); dot = fmaf(a.y, b.y, dot);
                dot = fmaf(a.z, b.z, dot); dot = fmaf(a.w, b.w, dot);
            }
            float kd = __fsub_rn(__fadd_rn(sqr, sq[rbase + c]), __fmul_rn(2.0f, dot));
            kdf[r*68 + m] = kd;
            cand[r*68 + 32 + m] = (unsigned int)c;
        }
    }
    __syncthreads();

    // exact top-16 with (key, idx) ordering
    if (t < 64) {
        float* kdf = (float*)cand;
        float dk[KNN]; int di[KNN];
#pragma unroll
        for (int j = 0; j < KNN; ++j) { dk[j] = FLT_MAX; di[j] = 0x7fffffff; }
        for (int m = 0; m < NCAND; ++m) {
            float kd = kdf[t*68 + m];
            int c = (int)cand[t*68 + 32 + m];
            bool better = (kd < dk[KNN-1]) || (kd == dk[KNN-1] && c < di[KNN-1]);
            if (better) {
#pragma unroll
                for (int j = KNN-1; j >= 1; --j) {
                    bool sh = (dk[j-1] > kd) || (dk[j-1] == kd && di[j-1] > c);
                    bool pl = (!sh) && ((dk[j] > kd) || (dk[j] == kd && di[j] > c));
                    float nk = sh ? dk[j-1] : (pl ? kd : dk[j]);
                    int ni = sh ? di[j-1] : (pl ? c : di[j]);
                    dk[j] = nk; di[j] = ni;
                }
                if ((dk[0] > kd) || (dk[0] == kd && di[0] > c)) { dk[0] = kd; di[0] = c; }
            }
        }
#pragma unroll
        for (int k = 0; k < KNN; ++k) nbr[(size_t)(r0g + t)*16 + k] = di[k];
    }
}

// Kernel 3: out[n,o] = relu(out[n,o] + max_k Bv[nbr_k, o])   (out holds A from k1)
__global__ __launch_bounds__(256) void k_combine(const float* __restrict__ Bvv,
    const int* __restrict__ nbr, float* __restrict__ out)
{
    int t = threadIdx.x;
    int row = blockIdx.x*4 + (t >> 6);
    int o = t & 63;
    int rb = (row >> 11) << 11;
    float m = -FLT_MAX;
#pragma unroll
    for (int k = 0; k < 16; ++k) {
        int c = nbr[(size_t)row*16 + k];
        m = fmaxf(m, Bvv[(size_t)(rb + c)*64 + o]);
    }
    out[(size_t)row*64 + o] = fmaxf(out[(size_t)row*64 + o] + m, 0.f);
}

extern "C" void kernel_launch(void* const* d_in, const int* in_sizes, int n_in,
                              void* d_out, int out_size, void* d_ws, size_t ws_size,
                              hipStream_t stream) {
    const float* x    = (const float*)d_in[0];
    // d_in[1] = batch (contiguous per batch; unused)
    const float* w    = (const float*)d_in[2];
    const float* bias = (const float*)d_in[3];
    float* out = (float*)d_out;

    float* Bvv  = (float*)d_ws;                       // 32 MB
    float* sqnp = Bvv + (size_t)NTOT * 64;            // 0.5 MB
    int*   nbr  = (int*)(sqnp + NTOT);                // 8 MB
    unsigned int* xbu = (unsigned int*)(nbr + (size_t)NTOT * 16);   // 16 MB bf16 x

    k_transform<<<NTOT/256, 256, 0, stream>>>((const float4*)x, w, bias, out, Bvv, sqnp, (uint4*)xbu);
    k_topk<<<2048, 256, 0, stream>>>((const float4*)x, (const uint4*)xbu, sqnp, nbr);
    k_combine<<<NTOT/4, 256, 0, stream>>>(Bvv, nbr, out);
}